// Round 8
// baseline (387.765 us; speedup 1.0000x reference)
//
#include <hip/hip_runtime.h>
#include <math.h>

#define BINS 10

// Problem constants: BATCH=8388608, NUM_CLASSES=2
constexpr int   NPAIRS = 4194304;       // float4 quads (2 rows x 2 classes each)
constexpr float NTOT_F = 16777216.0f;   // BATCH * NUM_CLASSES

constexpr int G1     = 2048;
constexpr int BLK    = 256;
constexpr int STRIDE = G1 * BLK;        // 524288
constexpr int ITERS  = NPAIRS / STRIDE; // 8 exact -> 32 el/thread (6-bit fields safe)

constexpr int SLOTS = 19;               // 0..8 = S_b, 9 = sumL, 10..18 = C_b (as float)

// Workspace: arr[slot*G1 + block] f32 (19*2048*4 = 155648 B), ticket u32 after.
constexpr size_t WS_ARR    = 0;
constexpr size_t WS_TICKET = 160000;    // 16-aligned, past arr

// Hot-path lessons: LDS f32 atomics ~3x trap (R4), ballot/popc counts regress
// (R7: SALU shares the wave's issue stream), LDS RMW latency-chains (R2/R3).
// Fast path = VGPR cndmask accumulators + packed-u64 counts (R5/R6).
__device__ __forceinline__ void proc(float x, bool y1,
                                     float* __restrict__ acc, float& sumL,
                                     unsigned long long& cnt64) {
    // z = (y==1) ? -x : x ; t = e^z ; u = 1+t
    // g = |sigmoid(x)-y| = t/u ; bce = max(x,0)-x*y+log1p(e^-|x|) = ln(u)
    float z = y1 ? -x : x;
    float t = __builtin_amdgcn_exp2f(z * 1.4426950408889634f);
    float u = 1.0f + t;
    float g = t * __builtin_amdgcn_rcpf(u);
    int   b = (int)(g * 9.9999f);        // g in [0,1] -> trunc == floor
    b = b < 9 ? b : 9;                   // clamp (rcp rounding safety)
    float l = __builtin_amdgcn_logf(u);  // log2(u); ln2 applied once at the end
    sumL += l;                           // bin9 recovered: S9 = sumL - sum(S0..8)
    cnt64 += 1ull << (6 * b);            // fields 0..8 used; field 9 ignored
#pragma unroll
    for (int i = 0; i < BINS - 1; ++i)   // v_cmp + v_cndmask + v_add per bin
        acc[i] += (b == i) ? l : 0.0f;
}

__global__ __launch_bounds__(BLK) void ghm_fused(const float4* __restrict__ x4,
                                                 const int2*   __restrict__ t2,
                                                 float*        __restrict__ arr,
                                                 unsigned*     __restrict__ ticket,
                                                 float*        __restrict__ out) {
    const int tid  = threadIdx.x;
    const int lane = tid & 63;
    const int wave = tid >> 6;

    float acc[BINS - 1];
#pragma unroll
    for (int b = 0; b < BINS - 1; ++b) acc[b] = 0.0f;
    float sumL = 0.0f;
    unsigned long long cnt64 = 0ull;

    const int base = blockIdx.x * BLK + tid;
#pragma unroll
    for (int k = 0; k < ITERS; ++k) {
        float4 xv = x4[base + k * STRIDE];
        int2   tv = t2[base + k * STRIDE];
        // element (row, c): y = (target[row] == c)
        proc(xv.x, tv.x == 0, acc, sumL, cnt64);
        proc(xv.y, tv.x == 1, acc, sumL, cnt64);
        proc(xv.z, tv.y == 0, acc, sumL, cnt64);
        proc(xv.w, tv.y == 1, acc, sumL, cnt64);
    }

    // ---- block reduce through conflict-free LDS columns (19 slots) ----
    __shared__ float cols[SLOTS * BLK];   // 19456 B -> 8 blocks/CU
#pragma unroll
    for (int b = 0; b < BINS - 1; ++b) cols[b * BLK + tid] = acc[b];
    cols[9 * BLK + tid] = sumL;
#pragma unroll
    for (int b = 0; b < BINS - 1; ++b)
        cols[(10 + b) * BLK + tid] = (float)((cnt64 >> (6 * b)) & 63ull);
    __syncthreads();

    // wave w reduces slots {w, w+4, w+8, ...}: 4 strided reads + shuffle tree
    for (int s = wave; s < SLOTS; s += 4) {
        float v = cols[s * BLK + lane]       + cols[s * BLK + lane + 64]
                + cols[s * BLK + lane + 128] + cols[s * BLK + lane + 192];
        for (int off = 32; off > 0; off >>= 1) v += __shfl_down(v, off, 64);
        if (lane == 0) arr[s * G1 + blockIdx.x] = v;   // slot-major
    }

    // ---- last-block-done final reduce (saves a kernel launch) ----
    __shared__ int amLast;
    __syncthreads();
    __threadfence();                       // make arr writes device-visible
    if (tid == 0) {
        unsigned old = atomicAdd(ticket, 1u);   // device-scope
        amLast = (old == (unsigned)(G1 - 1)) ? 1 : 0;
    }
    __syncthreads();
    if (!amLast) return;
    __threadfence();                       // acquire: see all blocks' arr writes

    // wave w reduces slots {w, w+4, ...}: lane l sums arr[s][l + 64k], k<32
    __shared__ double Red[SLOTS];
    for (int s = wave; s < SLOTS; s += 4) {
        double v = 0.0;
#pragma unroll
        for (int k = 0; k < G1 / 64; ++k) v += (double)arr[s * G1 + k * 64 + lane];
        for (int off = 32; off > 0; off >>= 1) v += __shfl_down(v, off, 64);
        if (lane == 0) Red[s] = v;
    }
    __syncthreads();
    if (tid == 0) {
        double Sb[BINS], Cb[BINS];
        double s9 = Red[9], c9 = (double)NTOT_F;
#pragma unroll
        for (int b = 0; b < BINS - 1; ++b) {
            Sb[b] = Red[b];      s9 -= Red[b];
            Cb[b] = Red[10 + b]; c9 -= Red[10 + b];
        }
        Sb[9] = s9; Cb[9] = c9;
        float nonempty = 0.0f;
#pragma unroll
        for (int b = 0; b < BINS; ++b) nonempty += (Cb[b] > 0.0) ? 1.0f : 0.0f;
        double tot = 0.0;
#pragma unroll
        for (int b = 0; b < BINS; ++b) {
            float gd   = fmaxf((float)Cb[b] * nonempty, 0.0001f);  // ref fp32 math
            float beta = NTOT_F / gd;
            tot += (double)beta * Sb[b];
        }
        // bce sums kept in log2; apply ln2 once, then mean
        out[0] = (float)(tot * 0.693147180559945309 / (double)NTOT_F);
    }
}

extern "C" void kernel_launch(void* const* d_in, const int* in_sizes, int n_in,
                              void* d_out, int out_size, void* d_ws, size_t ws_size,
                              hipStream_t stream) {
    const float4* x4 = (const float4*)d_in[0];   // [B,2] fp32 -> 2 rows per float4
    const int2*   t2 = (const int2*)d_in[1];     // int32 targets -> 2 rows per int2

    float*    arr    = (float*)   ((char*)d_ws + WS_ARR);
    unsigned* ticket = (unsigned*)((char*)d_ws + WS_TICKET);
    float*    out    = (float*)d_out;

    // ws is poisoned 0xAA before every timed launch -> zero the ticket on-stream
    // (hipMemsetAsync is graph-capturable; harness itself uses it).
    hipMemsetAsync(ticket, 0, sizeof(unsigned), stream);
    ghm_fused<<<G1, BLK, 0, stream>>>(x4, t2, arr, ticket, out);
}

// Round 9
// 120.452 us; speedup vs baseline: 3.2192x; 3.2192x over previous
//
#include <hip/hip_runtime.h>
#include <math.h>

#define BINS 10

// Problem constants: BATCH=8388608, NUM_CLASSES=2
constexpr int   NPAIRS = 4194304;       // float4 quads (2 rows x 2 classes each)
constexpr float NTOT_F = 16777216.0f;   // BATCH * NUM_CLASSES

constexpr int G1      = 2048;
constexpr int BLK     = 256;
constexpr int NTHREAD = G1 * BLK;             // 524288
constexpr int NCHUNK  = NPAIRS / 2;           // 2097152 chunks of 2 quads (8 el)
constexpr int ITERS   = NCHUNK / NTHREAD;     // 4 exact -> 32 el/thread (6-bit safe)

constexpr int SLOTS = 19;   // 0..8 = S_b, 9 = sumL, 10..18 = C_b (as float)

// Workspace: arr[slot*G1 + block] f32 = 19*2048*4 = 155648 B
constexpr size_t WS_ARR = 0;

// Hot-path ledger (main-kernel µs): LDS f32 atomics 92 (R4), fused+device-fence
// 180 (R8), ballot/popc 44 (R7), LDS RMW 37 (R2/3), VGPR cndmask + packed-u64
// counts ~28 (R5/R6 -- fastest). Keep the R5/R6 path; 9-bin select + algebraic
// bin 9 shaves 2 VALU/el.
__device__ __forceinline__ void proc(float x, bool y1,
                                     float* __restrict__ acc, float& sumL,
                                     unsigned long long& cnt64) {
    // z = (y==1) ? -x : x ; t = e^z ; u = 1+t
    // g = |sigmoid(x)-y| = t/u ; bce = max(x,0)-x*y+log1p(e^-|x|) = ln(u)
    float z = y1 ? -x : x;
    float t = __builtin_amdgcn_exp2f(z * 1.4426950408889634f);
    float u = 1.0f + t;
    float g = t * __builtin_amdgcn_rcpf(u);
    int   b = (int)(g * 9.9999f);        // g in [0,1] -> trunc == floor
    b = b < 9 ? b : 9;                   // clamp (rcp rounding safety)
    float l = __builtin_amdgcn_logf(u);  // log2(u); ln2 applied once at the end
    sumL += l;                           // S9 = sumL - sum(S0..8), C9 = N - sumC
    cnt64 += 1ull << (6 * b);            // fields 0..8 used; field 9 ignored
#pragma unroll
    for (int i = 0; i < BINS - 1; ++i)   // v_cmp + v_cndmask + v_add per bin
        acc[i] += (b == i) ? l : 0.0f;
}

__global__ __launch_bounds__(BLK) void ghm_main(const float4* __restrict__ x4,
                                                const int4*   __restrict__ t4,
                                                float*        __restrict__ arr) {
    const int tid  = threadIdx.x;
    const int lane = tid & 63;
    const int wave = tid >> 6;

    float acc[BINS - 1];
#pragma unroll
    for (int b = 0; b < BINS - 1; ++b) acc[b] = 0.0f;
    float sumL = 0.0f;
    unsigned long long cnt64 = 0ull;

    // chunk c covers quads {2c, 2c+1}: two dwordx4 x-loads + ONE dwordx4 t-load
    const int cbase = blockIdx.x * BLK + tid;
#pragma unroll
    for (int k = 0; k < ITERS; ++k) {
        int c = cbase + k * NTHREAD;
        float4 xa = x4[2 * c];
        float4 xb = x4[2 * c + 1];
        int4   tv = t4[c];
        // element (row, cls): y = (target[row] == cls)
        proc(xa.x, tv.x == 0, acc, sumL, cnt64);
        proc(xa.y, tv.x == 1, acc, sumL, cnt64);
        proc(xa.z, tv.y == 0, acc, sumL, cnt64);
        proc(xa.w, tv.y == 1, acc, sumL, cnt64);
        proc(xb.x, tv.z == 0, acc, sumL, cnt64);
        proc(xb.y, tv.z == 1, acc, sumL, cnt64);
        proc(xb.z, tv.w == 0, acc, sumL, cnt64);
        proc(xb.w, tv.w == 1, acc, sumL, cnt64);
    }

    // ---- block reduce through conflict-free LDS columns (19 slots) ----
    __shared__ float cols[SLOTS * BLK];   // 19456 B -> 8 blocks/CU
#pragma unroll
    for (int b = 0; b < BINS - 1; ++b) cols[b * BLK + tid] = acc[b];
    cols[9 * BLK + tid] = sumL;
#pragma unroll
    for (int b = 0; b < BINS - 1; ++b)
        cols[(10 + b) * BLK + tid] = (float)((cnt64 >> (6 * b)) & 63ull);
    __syncthreads();

    // wave w reduces slots {w, w+4, ...}: 4 strided reads + 6-step shuffle tree
    for (int s = wave; s < SLOTS; s += 4) {
        float v = cols[s * BLK + lane]       + cols[s * BLK + lane + 64]
                + cols[s * BLK + lane + 128] + cols[s * BLK + lane + 192];
        for (int off = 32; off > 0; off >>= 1) v += __shfl_down(v, off, 64);
        if (lane == 0) arr[s * G1 + blockIdx.x] = v;   // slot-major for final
    }
}

// Final: 19 waves? No -- 10 waves, wave w handles slots {w, w+4, ...} like main.
// Fully-unrolled independent loads, f64 shuffle reduce; thread 0 recovers bin 9,
// forms beta per reference fp32 arithmetic, writes the mean. Deterministic.
__global__ __launch_bounds__(640) void ghm_final(const float* __restrict__ arr,
                                                 float*       __restrict__ out) {
    const int wave = threadIdx.x >> 6;   // 0..9
    const int lane = threadIdx.x & 63;
    __shared__ double Red[SLOTS];
    for (int s = wave; s < SLOTS; s += 10) {
        double v = 0.0;
#pragma unroll
        for (int k = 0; k < G1 / 64; ++k) v += (double)arr[s * G1 + k * 64 + lane];
        for (int off = 32; off > 0; off >>= 1) v += __shfl_down(v, off, 64);
        if (lane == 0) Red[s] = v;
    }
    __syncthreads();
    if (threadIdx.x == 0) {
        double Sb[BINS], Cb[BINS];
        double s9 = Red[9], c9 = (double)NTOT_F;
#pragma unroll
        for (int b = 0; b < BINS - 1; ++b) {
            Sb[b] = Red[b];      s9 -= Red[b];
            Cb[b] = Red[10 + b]; c9 -= Red[10 + b];
        }
        Sb[9] = s9; Cb[9] = c9;
        float nonempty = 0.0f;
#pragma unroll
        for (int b = 0; b < BINS; ++b) nonempty += (Cb[b] > 0.0) ? 1.0f : 0.0f;
        double tot = 0.0;
#pragma unroll
        for (int b = 0; b < BINS; ++b) {
            float gd   = fmaxf((float)Cb[b] * nonempty, 0.0001f);  // ref fp32 math
            float beta = NTOT_F / gd;
            tot += (double)beta * Sb[b];
        }
        // bce sums kept in log2; apply ln2 once, then mean
        out[0] = (float)(tot * 0.693147180559945309 / (double)NTOT_F);
    }
}

extern "C" void kernel_launch(void* const* d_in, const int* in_sizes, int n_in,
                              void* d_out, int out_size, void* d_ws, size_t ws_size,
                              hipStream_t stream) {
    const float4* x4 = (const float4*)d_in[0];   // [B,2] fp32 -> 2 rows per float4
    const int4*   t4 = (const int4*)d_in[1];     // int32 targets -> 4 rows per int4

    float* arr = (float*)((char*)d_ws + WS_ARR);
    float* out = (float*)d_out;

    ghm_main <<<G1, BLK, 0, stream>>>(x4, t4, arr);
    ghm_final<<<1, 640, 0, stream>>>(arr, out);
}

// Round 10
// 117.835 us; speedup vs baseline: 3.2907x; 1.0222x over previous
//
#include <hip/hip_runtime.h>
#include <math.h>

#define BINS 10

// Problem constants: BATCH=8388608, NUM_CLASSES=2
constexpr int   NPAIRS = 4194304;       // float4 quads (2 rows x 2 classes each)
constexpr float NTOT_F = 16777216.0f;   // BATCH * NUM_CLASSES

constexpr int G1      = 2048;
constexpr int BLK     = 256;
constexpr int NTHREAD = G1 * BLK;             // 524288
constexpr int NCHUNK  = NPAIRS / 2;           // 2097152 chunks of 2 quads (8 el)
constexpr int ITERS   = NCHUNK / NTHREAD;     // 4 exact -> 32 el/thread

constexpr int SLOTS = 19;   // 0..8 = P_1..P_9, 9 = sumL (=P_0), 10..18 = N_1..N_9

// Workspace: arr[slot*G1 + block] f32 = 19*2048*4 = 155648 B
constexpr size_t WS_ARR = 0;

// Prefix thresholds: bin>=i  <=>  g = t/(1+t) >= i/9.9999  <=>  t >= T_i,
// T_i = i/(9.9999-i) (host-computed in double, stored fp32).
__constant__ const float TH[9] = {
    0.11111234569273214f,   // 1/8.9999
    0.25000312503906297f,   // 2/7.9999
    0.42857755110787297f,   // 3/6.9999
    0.66667777796296605f,   // 4/5.9999
    1.00002000040000800f,   // 5/4.9999
    1.50003750093752340f,   // 6/3.9999
    2.33341111370379013f,   // 7/2.9999
    4.00020001000050002f,   // 8/1.9999
    9.00090009000900090f    // 9/0.9999
};

// Hot-path ledger (main-kernel µs): LDS f32 atomics 92 (R4), fused+device-fence
// 180 (R8), ballot/popc 44 (R7), LDS RMW 37 (R2/3), VGPR cndmask 28-30 (R5/R9).
// R10: threshold-prefix binning deletes rcp/cvt/min/packed-count (~26 cyc/wave-el)
// for 9 addc (~18) -- one v_cmp per bin feeds BOTH the sum cndmask and the count.
__device__ __forceinline__ void proc(float x, bool y1,
                                     float* __restrict__ P, float& sumL,
                                     unsigned* __restrict__ N) {
    // z = (y==1) ? -x : x ; t = e^z ; bce = ln(1+t) = ln2*log2(1+t)
    float z = y1 ? -x : x;
    float t = __builtin_amdgcn_exp2f(z * 1.4426950408889634f);
    float u = 1.0f + t;
    float l = __builtin_amdgcn_logf(u);  // log2(u); ln2 applied once at the end
    sumL += l;                           // P_0
#pragma unroll
    for (int i = 0; i < BINS - 1; ++i) {
        bool hit = t >= TH[i];           // one v_cmp, shared by both accumulates
        P[i] += hit ? l : 0.0f;          // v_cndmask + v_add
        N[i] += hit ? 1u : 0u;           // v_addc (carry-in from the cmp)
    }
}

__global__ __launch_bounds__(BLK) void ghm_main(const float4* __restrict__ x4,
                                                const int4*   __restrict__ t4,
                                                float*        __restrict__ arr) {
    const int tid  = threadIdx.x;
    const int lane = tid & 63;
    const int wave = tid >> 6;

    float P[BINS - 1];
    unsigned N[BINS - 1];
#pragma unroll
    for (int b = 0; b < BINS - 1; ++b) { P[b] = 0.0f; N[b] = 0u; }
    float sumL = 0.0f;

    // chunk c covers quads {2c, 2c+1}: two dwordx4 x-loads + one dwordx4 t-load
    const int cbase = blockIdx.x * BLK + tid;
#pragma unroll
    for (int k = 0; k < ITERS; ++k) {
        int c = cbase + k * NTHREAD;
        float4 xa = x4[2 * c];
        float4 xb = x4[2 * c + 1];
        int4   tv = t4[c];
        // element (row, cls): y = (target[row] == cls)
        proc(xa.x, tv.x == 0, P, sumL, N);
        proc(xa.y, tv.x == 1, P, sumL, N);
        proc(xa.z, tv.y == 0, P, sumL, N);
        proc(xa.w, tv.y == 1, P, sumL, N);
        proc(xb.x, tv.z == 0, P, sumL, N);
        proc(xb.y, tv.z == 1, P, sumL, N);
        proc(xb.z, tv.w == 0, P, sumL, N);
        proc(xb.w, tv.w == 1, P, sumL, N);
    }

    // ---- block reduce through conflict-free LDS columns (19 slots) ----
    __shared__ float cols[SLOTS * BLK];   // 19456 B -> 8 blocks/CU (= 32-wave cap)
#pragma unroll
    for (int b = 0; b < BINS - 1; ++b) cols[b * BLK + tid] = P[b];
    cols[9 * BLK + tid] = sumL;
#pragma unroll
    for (int b = 0; b < BINS - 1; ++b)
        cols[(10 + b) * BLK + tid] = (float)N[b];   // <=32 -> exact in f32
    __syncthreads();

    // wave w reduces slots {w, w+4, ...}: 4 strided reads + 6-step shuffle tree
    for (int s = wave; s < SLOTS; s += 4) {
        float v = cols[s * BLK + lane]       + cols[s * BLK + lane + 64]
                + cols[s * BLK + lane + 128] + cols[s * BLK + lane + 192];
        for (int off = 32; off > 0; off >>= 1) v += __shfl_down(v, off, 64);
        if (lane == 0) arr[s * G1 + blockIdx.x] = v;   // slot-major for final
    }
}

// Final: 10 waves; wave w reduces slots {w, w+10}. Prefix->bin via adjacent
// differences in f64; thread 0 forms beta per reference fp32 arithmetic and
// writes the mean. Deterministic.
__global__ __launch_bounds__(640) void ghm_final(const float* __restrict__ arr,
                                                 float*       __restrict__ out) {
    const int wave = threadIdx.x >> 6;   // 0..9
    const int lane = threadIdx.x & 63;
    __shared__ double Red[SLOTS];
    for (int s = wave; s < SLOTS; s += 10) {
        double v = 0.0;
#pragma unroll
        for (int k = 0; k < G1 / 64; ++k) v += (double)arr[s * G1 + k * 64 + lane];
        for (int off = 32; off > 0; off >>= 1) v += __shfl_down(v, off, 64);
        if (lane == 0) Red[s] = v;
    }
    __syncthreads();
    if (threadIdx.x == 0) {
        // prefix arrays: Pp[0]=sumL, Pp[1..9]=Red[0..8], Pp[10]=0; same for counts
        double Pp[BINS + 1], Np[BINS + 1];
        Pp[0] = Red[9];            Np[0] = (double)NTOT_F;
#pragma unroll
        for (int i = 1; i <= 9; ++i) { Pp[i] = Red[i - 1]; Np[i] = Red[9 + i]; }
        Pp[10] = 0.0; Np[10] = 0.0;

        double Sb[BINS], Cb[BINS];
#pragma unroll
        for (int b = 0; b < BINS; ++b) {
            Sb[b] = Pp[b] - Pp[b + 1];
            Cb[b] = Np[b] - Np[b + 1];
        }
        float nonempty = 0.0f;
#pragma unroll
        for (int b = 0; b < BINS; ++b) nonempty += (Cb[b] > 0.0) ? 1.0f : 0.0f;
        double tot = 0.0;
#pragma unroll
        for (int b = 0; b < BINS; ++b) {
            float gd   = fmaxf((float)Cb[b] * nonempty, 0.0001f);  // ref fp32 math
            float beta = NTOT_F / gd;
            tot += (double)beta * Sb[b];
        }
        // bce sums kept in log2; apply ln2 once, then mean
        out[0] = (float)(tot * 0.693147180559945309 / (double)NTOT_F);
    }
}

extern "C" void kernel_launch(void* const* d_in, const int* in_sizes, int n_in,
                              void* d_out, int out_size, void* d_ws, size_t ws_size,
                              hipStream_t stream) {
    const float4* x4 = (const float4*)d_in[0];   // [B,2] fp32 -> 2 rows per float4
    const int4*   t4 = (const int4*)d_in[1];     // int32 targets -> 4 rows per int4

    float* arr = (float*)((char*)d_ws + WS_ARR);
    float* out = (float*)d_out;

    ghm_main <<<G1, BLK, 0, stream>>>(x4, t4, arr);
    ghm_final<<<1, 640, 0, stream>>>(arr, out);
}